// Round 1
// baseline (904.536 us; speedup 1.0000x reference)
//
#include <hip/hip_runtime.h>
#include <stdint.h>

typedef unsigned short u16;
typedef short bf16x8 __attribute__((ext_vector_type(8)));
typedef float f32x4 __attribute__((ext_vector_type(4)));

constexpr int B_ = 2, V_ = 50000, E_ = 400000;
constexpr int FIN_ = 128, COND_ = 32, HID_ = 256, OUT_ = 128, ENC_ = 64;
constexpr int M_ = B_ * V_;          // 100000
constexpr int K0_ = FIN_ + COND_;    // 160
constexpr float EPS_ = 1e-5f;

#define DEV static __device__ __forceinline__

DEV float b2f(u16 u) { union { float f; uint32_t i; } x; x.i = ((uint32_t)u) << 16; return x.f; }
DEV u16 f2b(float f) {
  union { float f; uint32_t i; } x; x.f = f;
  uint32_t r = x.i + 0x7fffu + ((x.i >> 16) & 1u);
  return (u16)(r >> 16);
}

// ---------------- graph preprocessing ----------------
__global__ void k_count(const int* __restrict__ dst, int* __restrict__ cnt) {
  int e = blockIdx.x * blockDim.x + threadIdx.x;
  if (e < E_) atomicAdd(&cnt[dst[e]], 1);
}

__global__ void k_dinv(const int* __restrict__ cnt, float* __restrict__ dinv) {
  int v = blockIdx.x * blockDim.x + threadIdx.x;
  if (v < V_) dinv[v] = rsqrtf(1.0f + (float)cnt[v]);
}

__global__ void k_scan(const int* __restrict__ cnt, int* __restrict__ row_ptr,
                       int* __restrict__ cursor) {
  __shared__ int s[1024];
  __shared__ int carry_s;
  int tid = threadIdx.x;
  if (tid == 0) { carry_s = 0; row_ptr[0] = 0; }
  __syncthreads();
  for (int base = 0; base < V_; base += 1024) {
    int i = base + tid;
    int val = (i < V_) ? cnt[i] : 0;
    s[tid] = val;
    __syncthreads();
    for (int off = 1; off < 1024; off <<= 1) {
      int t = (tid >= off) ? s[tid - off] : 0;
      __syncthreads();
      s[tid] += t;
      __syncthreads();
    }
    int carry = carry_s;
    int incl = s[tid] + carry;
    if (i < V_) { row_ptr[i + 1] = incl; cursor[i] = incl - val; }
    __syncthreads();
    if (tid == 1023) carry_s = incl;
    __syncthreads();
  }
}

__global__ void k_fill(const int* __restrict__ src, const int* __restrict__ dst,
                       int* __restrict__ cursor, int* __restrict__ csr_src) {
  int e = blockIdx.x * blockDim.x + threadIdx.x;
  if (e < E_) {
    int p = atomicAdd(&cursor[dst[e]], 1);
    csr_src[p] = src[e];
  }
}

// ---------------- small dense helpers ----------------
__global__ void k_film(const float* __restrict__ t, const float* __restrict__ fw,
                       const float* __restrict__ fb, float* __restrict__ gb) {
  int b = blockIdx.x; int j = threadIdx.x;   // blockDim = 512
  float acc = fb[j];
  for (int k = 0; k < ENC_; ++k) acc += t[b * ENC_ + k] * fw[k * 512 + j];
  gb[b * 512 + j] = acc;
}

__global__ void k_wconv(const float* __restrict__ W, u16* __restrict__ WT, int K, int N) {
  int idx = blockIdx.x * blockDim.x + threadIdx.x;
  if (idx < K * N) {
    int k = idx / N, n = idx % N;
    WT[n * K + k] = f2b(W[idx]);
  }
}

__global__ void k_prep0(const float* __restrict__ x, const float* __restrict__ cond,
                        u16* __restrict__ A0) {
  int idx = blockIdx.x * blockDim.x + threadIdx.x; // chunk of 4 elements
  if (idx >= M_ * K0_ / 4) return;
  int e = idx * 4;
  int r = e / K0_, c = e % K0_;
  float4 v;
  if (c < FIN_) v = *(const float4*)&x[(size_t)r * FIN_ + c];
  else { int vv = r % V_; v = *(const float4*)&cond[(size_t)vv * COND_ + (c - FIN_)]; }
  uint2 o;
  o.x = (uint32_t)f2b(v.x) | ((uint32_t)f2b(v.y) << 16);
  o.y = (uint32_t)f2b(v.z) | ((uint32_t)f2b(v.w) << 16);
  *(uint2*)&A0[e] = o;
}

// ---------------- GroupNorm stats ----------------
__global__ void k_gnstats(const u16* __restrict__ h, float* __restrict__ raw) {
  int b = blockIdx.y;
  const u16* p = h + (size_t)b * V_ * HID_;
  const int nvec = V_ * HID_ / 8;
  float s = 0.f, ss = 0.f;
  for (int i = blockIdx.x * blockDim.x + threadIdx.x; i < nvec; i += gridDim.x * blockDim.x) {
    uint4 u = *(const uint4*)&p[(size_t)i * 8];
    u16 us[8]; *(uint4*)us = u;
#pragma unroll
    for (int j = 0; j < 8; ++j) { float f = b2f(us[j]); s += f; ss += f * f; }
  }
  __shared__ float ls[256], lss[256];
  ls[threadIdx.x] = s; lss[threadIdx.x] = ss;
  __syncthreads();
  for (int off = 128; off > 0; off >>= 1) {
    if (threadIdx.x < off) { ls[threadIdx.x] += ls[threadIdx.x + off]; lss[threadIdx.x] += lss[threadIdx.x + off]; }
    __syncthreads();
  }
  if (threadIdx.x == 0) {
    atomicAdd(&raw[b * 2 + 0], ls[0]);
    atomicAdd(&raw[b * 2 + 1], lss[0]);
  }
}

__global__ void k_gnfinal(const float* __restrict__ raw, float* __restrict__ stats) {
  for (int b = 0; b < B_; ++b) {
    float n = (float)V_ * (float)HID_;
    float mu = raw[b * 2] / n;
    float var = raw[b * 2 + 1] / n - mu * mu;
    stats[b * 2 + 0] = mu;
    stats[b * 2 + 1] = rsqrtf(var + EPS_);
  }
}

// ---------------- GCN gather (CSR, fused self-loop+bias+relu) ----------------
__global__ __launch_bounds__(256) void k_gather(
    const u16* __restrict__ hw, const float* __restrict__ dinv,
    const int* __restrict__ row_ptr, const int* __restrict__ csr_src,
    const float* __restrict__ bias, u16* __restrict__ out, int do_relu)
{
  int v = blockIdx.x;
  int c = threadIdx.x;
  float dv = dinv[v];
  float sl = dv * dv;
  float a0 = b2f(hw[(size_t)v * HID_ + c]) * sl;
  float a1 = b2f(hw[(size_t)(V_ + v) * HID_ + c]) * sl;
  int beg = row_ptr[v], end = row_ptr[v + 1];
  for (int j = beg; j < end; ++j) {
    int s = csr_src[j];
    float cf = dinv[s] * dv;
    a0 += b2f(hw[(size_t)s * HID_ + c]) * cf;
    a1 += b2f(hw[(size_t)(V_ + s) * HID_ + c]) * cf;
  }
  float bc = bias[c];
  a0 += bc; a1 += bc;
  if (do_relu) { a0 = fmaxf(a0, 0.f); a1 = fmaxf(a1, 0.f); }
  out[(size_t)v * HID_ + c] = f2b(a0);
  out[(size_t)(V_ + v) * HID_ + c] = f2b(a1);
}

// ---------------- MFMA GEMM ----------------
// PRO: 0=plain bf16 A, 1=GroupNorm(A), 2=FiLM+relu(A)
// EPI: 0=store bf16, 1=bias+relu->bf16, 2=bias + x residual -> f32
template<int PRO, int EPI, int K, int N>
__global__ __launch_bounds__(256) void k_gemm(
    const u16* __restrict__ A, const u16* __restrict__ WT,
    const float* __restrict__ bias, const float* __restrict__ stats,
    const float* __restrict__ gng, const float* __restrict__ gnb,
    const float* __restrict__ gb, const float* __restrict__ xres,
    void* __restrict__ Out)
{
  constexpr int BM = 128, BN = 64, BK = 32;
  __shared__ u16 As[BM][BK + 8];
  __shared__ u16 Bs[BN][BK + 8];
  const int tile_m = blockIdx.x * BM;
  const int n0 = blockIdx.y * BN;
  const int tid = threadIdx.x;
  const int wave = tid >> 6, lane = tid & 63;
  const int wm = (wave >> 1) * 64, wn = (wave & 1) * 32;
  const int lr = lane & 15, lk = (lane >> 4) * 8;

  f32x4 acc[4][2];
#pragma unroll
  for (int i = 0; i < 4; ++i)
#pragma unroll
    for (int j = 0; j < 2; ++j) acc[i][j] = {0.f, 0.f, 0.f, 0.f};

  for (int kb = 0; kb < K; kb += BK) {
    // stage A tile (128x32 bf16)
#pragma unroll
    for (int it = 0; it < 2; ++it) {
      int c = tid + it * 256;
      int r = c >> 2, kq = (c & 3) * 8;
      int row = tile_m + r;
      uint4 val = {0u, 0u, 0u, 0u};
      if (row < M_) {
        val = *(const uint4*)&A[(size_t)row * K + kb + kq];
        if (PRO != 0) {
          int b = (row >= V_) ? 1 : 0;
          u16 us[8]; *(uint4*)us = val;
          float f[8];
#pragma unroll
          for (int j = 0; j < 8; ++j) f[j] = b2f(us[j]);
          if (PRO == 1) {
            float mu = stats[b * 2], rs = stats[b * 2 + 1];
#pragma unroll
            for (int j = 0; j < 8; ++j) {
              int ch = kb + kq + j;
              f[j] = (f[j] - mu) * rs * gng[ch] + gnb[ch];
            }
          } else {
#pragma unroll
            for (int j = 0; j < 8; ++j) {
              int ch = kb + kq + j;
              float y = f[j] * gb[b * 512 + ch] + gb[b * 512 + 256 + ch];
              f[j] = fmaxf(y, 0.f);
            }
          }
#pragma unroll
          for (int j = 0; j < 8; ++j) us[j] = f2b(f[j]);
          val = *(const uint4*)us;
        }
      }
      *(uint4*)&As[r][kq] = val;
    }
    // stage B tile (64x32 bf16) from pre-transposed WT [N][K]
    {
      int r = tid >> 2, kq = (tid & 3) * 8;
      uint4 val = *(const uint4*)&WT[(size_t)(n0 + r) * K + kb + kq];
      *(uint4*)&Bs[r][kq] = val;
    }
    __syncthreads();
    bf16x8 af[4], bfv[2];
#pragma unroll
    for (int fm = 0; fm < 4; ++fm) af[fm] = *(const bf16x8*)&As[wm + fm * 16 + lr][lk];
#pragma unroll
    for (int fn = 0; fn < 2; ++fn) bfv[fn] = *(const bf16x8*)&Bs[wn + fn * 16 + lr][lk];
#pragma unroll
    for (int fm = 0; fm < 4; ++fm)
#pragma unroll
      for (int fn = 0; fn < 2; ++fn)
        acc[fm][fn] = __builtin_amdgcn_mfma_f32_16x16x32_bf16(af[fm], bfv[fn], acc[fm][fn], 0, 0, 0);
    __syncthreads();
  }

#pragma unroll
  for (int fm = 0; fm < 4; ++fm) {
#pragma unroll
    for (int fn = 0; fn < 2; ++fn) {
#pragma unroll
      for (int j = 0; j < 4; ++j) {
        int row = tile_m + wm + fm * 16 + (lane >> 4) * 4 + j;
        int col = n0 + wn + fn * 16 + lr;
        if (row < M_) {
          float v = acc[fm][fn][j];
          if (EPI == 0) {
            ((u16*)Out)[(size_t)row * N + col] = f2b(v);
          } else if (EPI == 1) {
            v += bias[col]; v = fmaxf(v, 0.f);
            ((u16*)Out)[(size_t)row * N + col] = f2b(v);
          } else {
            v += bias[col] + xres[(size_t)row * N + col];
            ((float*)Out)[(size_t)row * N + col] = v;
          }
        }
      }
    }
  }
}

// ---------------- host ----------------
extern "C" void kernel_launch(void* const* d_in, const int* in_sizes, int n_in,
                              void* d_out, int out_size, void* d_ws, size_t ws_size,
                              hipStream_t stream) {
  (void)in_sizes; (void)n_in; (void)out_size; (void)ws_size;
  const float* x      = (const float*)d_in[0];
  const float* cond_x = (const float*)d_in[1];
  const float* t      = (const float*)d_in[3];
  const int*   ei     = (const int*)d_in[4];
  const float* w_c0 = (const float*)d_in[5];  const float* b_c0 = (const float*)d_in[6];
  const float* w_l0 = (const float*)d_in[7];  const float* b_l0 = (const float*)d_in[8];
  const float* w_c1 = (const float*)d_in[9];  const float* b_c1 = (const float*)d_in[10];
  const float* w_l1 = (const float*)d_in[11]; const float* b_l1 = (const float*)d_in[12];
  const float* w_c2 = (const float*)d_in[13]; const float* b_c2 = (const float*)d_in[14];
  const float* w_l2 = (const float*)d_in[15]; const float* b_l2 = (const float*)d_in[16];
  const float* gn_g = (const float*)d_in[17]; const float* gn_b = (const float*)d_in[18];
  const float* film_w = (const float*)d_in[19]; const float* film_b = (const float*)d_in[20];

  char* wsp = (char*)d_ws;
  size_t off = 0;
  auto alloc = [&](size_t bytes) -> char* {
    char* p = wsp + off; off += (bytes + 255) & ~(size_t)255; return p;
  };
  int*   cnt       = (int*)  alloc((size_t)V_ * 4);
  int*   row_ptr   = (int*)  alloc((size_t)(V_ + 1) * 4);
  int*   cursor    = (int*)  alloc((size_t)V_ * 4);
  int*   csr_src   = (int*)  alloc((size_t)E_ * 4);
  float* dinv      = (float*)alloc((size_t)V_ * 4);
  float* stats_raw = (float*)alloc(16);
  float* stats     = (float*)alloc(16);
  float* gb        = (float*)alloc(2 * 512 * 4);
  u16* wc0T = (u16*)alloc((size_t)256 * 160 * 2);
  u16* wl0T = (u16*)alloc((size_t)256 * 256 * 2);
  u16* wc1T = (u16*)alloc((size_t)256 * 256 * 2);
  u16* wl1T = (u16*)alloc((size_t)256 * 256 * 2);
  u16* wc2T = (u16*)alloc((size_t)256 * 256 * 2);
  u16* wl2T = (u16*)alloc((size_t)128 * 256 * 2);
  u16* A0   = (u16*)alloc((size_t)M_ * K0_ * 2);
  u16* HW   = (u16*)alloc((size_t)M_ * HID_ * 2);
  u16* HA   = (u16*)alloc((size_t)M_ * HID_ * 2);
  u16* HB   = (u16*)alloc((size_t)M_ * HID_ * 2);

  const int* srcI = ei;
  const int* dstI = ei + E_;

  hipMemsetAsync(cnt, 0, (size_t)V_ * 4, stream);
  hipMemsetAsync(stats_raw, 0, 16, stream);

  k_count<<<dim3((E_ + 255) / 256), dim3(256), 0, stream>>>(dstI, cnt);
  k_dinv <<<dim3((V_ + 255) / 256), dim3(256), 0, stream>>>(cnt, dinv);
  k_scan <<<dim3(1), dim3(1024), 0, stream>>>(cnt, row_ptr, cursor);
  k_fill <<<dim3((E_ + 255) / 256), dim3(256), 0, stream>>>(srcI, dstI, cursor, csr_src);
  k_film <<<dim3(2), dim3(512), 0, stream>>>(t, film_w, film_b, gb);

  k_wconv<<<dim3((160 * 256 + 255) / 256), dim3(256), 0, stream>>>(w_c0, wc0T, 160, 256);
  k_wconv<<<dim3((256 * 256 + 255) / 256), dim3(256), 0, stream>>>(w_l0, wl0T, 256, 256);
  k_wconv<<<dim3((256 * 256 + 255) / 256), dim3(256), 0, stream>>>(w_c1, wc1T, 256, 256);
  k_wconv<<<dim3((256 * 256 + 255) / 256), dim3(256), 0, stream>>>(w_l1, wl1T, 256, 256);
  k_wconv<<<dim3((256 * 256 + 255) / 256), dim3(256), 0, stream>>>(w_c2, wc2T, 256, 256);
  k_wconv<<<dim3((256 * 128 + 255) / 256), dim3(256), 0, stream>>>(w_l2, wl2T, 256, 128);

  k_prep0<<<dim3(M_ * K0_ / 4 / 256), dim3(256), 0, stream>>>(x, cond_x, A0);

  constexpr int GM = (M_ + 127) / 128;  // 782

  // layer 0: GCN(concat) -> relu ; Lin0 -> relu
  k_gemm<0, 0, 160, 256><<<dim3(GM, 4), 256, 0, stream>>>(A0, wc0T, nullptr, nullptr, nullptr, nullptr, nullptr, nullptr, HW);
  k_gather<<<dim3(V_), 256, 0, stream>>>(HW, dinv, row_ptr, csr_src, b_c0, HA, 1);
  k_gemm<0, 1, 256, 256><<<dim3(GM, 4), 256, 0, stream>>>(HA, wl0T, b_l0, nullptr, nullptr, nullptr, nullptr, nullptr, HB);

  // GroupNorm stats (normalization fused into next GEMM's A-load)
  k_gnstats<<<dim3(1024, 2), 256, 0, stream>>>(HB, stats_raw);
  k_gnfinal<<<dim3(1), dim3(1), 0, stream>>>(stats_raw, stats);

  // layer 1: GCN(gn(h)) -> relu ; Lin1 -> relu
  k_gemm<1, 0, 256, 256><<<dim3(GM, 4), 256, 0, stream>>>(HB, wc1T, nullptr, stats, gn_g, gn_b, nullptr, nullptr, HW);
  k_gather<<<dim3(V_), 256, 0, stream>>>(HW, dinv, row_ptr, csr_src, b_c1, HA, 1);
  k_gemm<0, 1, 256, 256><<<dim3(GM, 4), 256, 0, stream>>>(HA, wl1T, b_l1, nullptr, nullptr, nullptr, nullptr, nullptr, HB);

  // layer 2: GCN (bias, no relu) ; FiLM+relu fused into final GEMM A-load
  k_gemm<0, 0, 256, 256><<<dim3(GM, 4), 256, 0, stream>>>(HB, wc2T, nullptr, nullptr, nullptr, nullptr, nullptr, nullptr, HW);
  k_gather<<<dim3(V_), 256, 0, stream>>>(HW, dinv, row_ptr, csr_src, b_c2, HA, 0);
  k_gemm<2, 2, 256, 128><<<dim3(GM, 2), 256, 0, stream>>>(HA, wl2T, b_l2, nullptr, nullptr, nullptr, gb, x, (void*)d_out);
}

// Round 2
// 832.754 us; speedup vs baseline: 1.0862x; 1.0862x over previous
//
#include <hip/hip_runtime.h>
#include <stdint.h>

typedef unsigned short u16;
typedef short bf16x8 __attribute__((ext_vector_type(8)));
typedef float f32x4 __attribute__((ext_vector_type(4)));

constexpr int B_ = 2, V_ = 50000, E_ = 400000;
constexpr int FIN_ = 128, COND_ = 32, HID_ = 256, OUT_ = 128, ENC_ = 64;
constexpr int M_ = B_ * V_;          // 100000
constexpr int K0_ = FIN_ + COND_;    // 160
constexpr float EPS_ = 1e-5f;

#define DEV static __device__ __forceinline__

DEV float b2f(u16 u) { union { float f; uint32_t i; } x; x.i = ((uint32_t)u) << 16; return x.f; }
DEV u16 f2b(float f) {
  union { float f; uint32_t i; } x; x.f = f;
  uint32_t r = x.i + 0x7fffu + ((x.i >> 16) & 1u);
  return (u16)(r >> 16);
}

// ---------------- graph preprocessing ----------------
__global__ void k_count(const int* __restrict__ dst, int* __restrict__ cnt) {
  int e = blockIdx.x * blockDim.x + threadIdx.x;
  if (e < E_) atomicAdd(&cnt[dst[e]], 1);
}

__global__ void k_dinv(const int* __restrict__ cnt, float* __restrict__ dinv) {
  int v = blockIdx.x * blockDim.x + threadIdx.x;
  if (v < V_) dinv[v] = rsqrtf(1.0f + (float)cnt[v]);
}

__global__ void k_scan(const int* __restrict__ cnt, int* __restrict__ row_ptr,
                       int* __restrict__ cursor) {
  __shared__ int s[1024];
  __shared__ int carry_s;
  int tid = threadIdx.x;
  if (tid == 0) { carry_s = 0; row_ptr[0] = 0; }
  __syncthreads();
  for (int base = 0; base < V_; base += 1024) {
    int i = base + tid;
    int val = (i < V_) ? cnt[i] : 0;
    s[tid] = val;
    __syncthreads();
    for (int off = 1; off < 1024; off <<= 1) {
      int t = (tid >= off) ? s[tid - off] : 0;
      __syncthreads();
      s[tid] += t;
      __syncthreads();
    }
    int carry = carry_s;
    int incl = s[tid] + carry;
    if (i < V_) { row_ptr[i + 1] = incl; cursor[i] = incl - val; }
    __syncthreads();
    if (tid == 1023) carry_s = incl;
    __syncthreads();
  }
}

__global__ void k_fill(const int* __restrict__ src, const int* __restrict__ dst,
                       int* __restrict__ cursor, int* __restrict__ csr_src) {
  int e = blockIdx.x * blockDim.x + threadIdx.x;
  if (e < E_) {
    int p = atomicAdd(&cursor[dst[e]], 1);
    csr_src[p] = src[e];
  }
}

// ---------------- small dense helpers ----------------
__global__ void k_film(const float* __restrict__ t, const float* __restrict__ fw,
                       const float* __restrict__ fb, float* __restrict__ gb) {
  int b = blockIdx.x; int j = threadIdx.x;   // blockDim = 512
  float acc = fb[j];
  for (int k = 0; k < ENC_; ++k) acc += t[b * ENC_ + k] * fw[k * 512 + j];
  gb[b * 512 + j] = acc;
}

__global__ void k_wconv(const float* __restrict__ W, u16* __restrict__ WT, int K, int N) {
  int idx = blockIdx.x * blockDim.x + threadIdx.x;
  if (idx < K * N) {
    int k = idx / N, n = idx % N;
    WT[n * K + k] = f2b(W[idx]);
  }
}

__global__ void k_prep0(const float* __restrict__ x, const float* __restrict__ cond,
                        u16* __restrict__ A0) {
  int idx = blockIdx.x * blockDim.x + threadIdx.x; // chunk of 4 elements
  if (idx >= M_ * K0_ / 4) return;
  int e = idx * 4;
  int r = e / K0_, c = e % K0_;
  float4 v;
  if (c < FIN_) v = *(const float4*)&x[(size_t)r * FIN_ + c];
  else { int vv = r % V_; v = *(const float4*)&cond[(size_t)vv * COND_ + (c - FIN_)]; }
  uint2 o;
  o.x = (uint32_t)f2b(v.x) | ((uint32_t)f2b(v.y) << 16);
  o.y = (uint32_t)f2b(v.z) | ((uint32_t)f2b(v.w) << 16);
  *(uint2*)&A0[e] = o;
}

// ---------------- GroupNorm stats ----------------
__global__ void k_gnstats(const u16* __restrict__ h, float* __restrict__ raw) {
  int b = blockIdx.y;
  const u16* p = h + (size_t)b * V_ * HID_;
  const int nvec = V_ * HID_ / 8;
  float s = 0.f, ss = 0.f;
  for (int i = blockIdx.x * blockDim.x + threadIdx.x; i < nvec; i += gridDim.x * blockDim.x) {
    uint4 u = *(const uint4*)&p[(size_t)i * 8];
    u16 us[8]; *(uint4*)us = u;
#pragma unroll
    for (int j = 0; j < 8; ++j) { float f = b2f(us[j]); s += f; ss += f * f; }
  }
  __shared__ float ls[256], lss[256];
  ls[threadIdx.x] = s; lss[threadIdx.x] = ss;
  __syncthreads();
  for (int off = 128; off > 0; off >>= 1) {
    if (threadIdx.x < off) { ls[threadIdx.x] += ls[threadIdx.x + off]; lss[threadIdx.x] += lss[threadIdx.x + off]; }
    __syncthreads();
  }
  if (threadIdx.x == 0) {
    atomicAdd(&raw[b * 2 + 0], ls[0]);
    atomicAdd(&raw[b * 2 + 1], lss[0]);
  }
}

__global__ void k_gnfinal(const float* __restrict__ raw, float* __restrict__ stats) {
  for (int b = 0; b < B_; ++b) {
    float n = (float)V_ * (float)HID_;
    float mu = raw[b * 2] / n;
    float var = raw[b * 2 + 1] / n - mu * mu;
    stats[b * 2 + 0] = mu;
    stats[b * 2 + 1] = rsqrtf(var + EPS_);
  }
}

// ---------------- GCN gather (CSR, neighbor-parallel, fused self-loop+bias+relu) ----
// Block layout: 256 threads = [nb=4 neighbor groups (waves)] x [b=2 batches] x [32 ch threads]
// Each thread accumulates 8 channels (uint4 = 16B loads). LDS-reduce over nb.
__global__ __launch_bounds__(256) void k_gather(
    const u16* __restrict__ hw, const float* __restrict__ dinv,
    const int* __restrict__ row_ptr, const int* __restrict__ csr_src,
    const float* __restrict__ bias, u16* __restrict__ out, int do_relu)
{
  __shared__ float red[3][2][HID_];   // 6 KB: partials of nb groups 1..3
  const int v   = blockIdx.x;
  const int tid = threadIdx.x;
  const int nb  = tid >> 6;          // wave id: neighbor group 0..3
  const int b   = (tid >> 5) & 1;    // batch
  const int c0  = (tid & 31) * 8;    // channel base (8 per thread)

  const float dv = dinv[v];
  const int beg = row_ptr[v], end = row_ptr[v + 1];

  float acc[8];
#pragma unroll
  for (int k = 0; k < 8; ++k) acc[k] = 0.f;

  for (int j = beg + nb; j < end; j += 4) {
    int s = csr_src[j];
    float cf = dinv[s] * dv;
    uint4 u = *(const uint4*)&hw[((size_t)b * V_ + s) * HID_ + c0];
    u16 us[8]; *(uint4*)us = u;
#pragma unroll
    for (int k = 0; k < 8; ++k) acc[k] += b2f(us[k]) * cf;
  }

  if (nb > 0) {
#pragma unroll
    for (int k = 0; k < 8; k += 4)
      *(float4*)&red[nb - 1][b][c0 + k] = *(float4*)&acc[k];
  }
  __syncthreads();
  if (nb == 0) {
#pragma unroll
    for (int g = 0; g < 3; ++g)
#pragma unroll
      for (int k = 0; k < 8; ++k) acc[k] += red[g][b][c0 + k];

    // self-loop + bias (+ relu)
    float sl = dv * dv;
    uint4 u = *(const uint4*)&hw[((size_t)b * V_ + v) * HID_ + c0];
    u16 us[8]; *(uint4*)us = u;
#pragma unroll
    for (int k = 0; k < 8; ++k) {
      float a = acc[k] + b2f(us[k]) * sl + bias[c0 + k];
      if (do_relu) a = fmaxf(a, 0.f);
      acc[k] = a;
    }
    uint4 o;
    o.x = (uint32_t)f2b(acc[0]) | ((uint32_t)f2b(acc[1]) << 16);
    o.y = (uint32_t)f2b(acc[2]) | ((uint32_t)f2b(acc[3]) << 16);
    o.z = (uint32_t)f2b(acc[4]) | ((uint32_t)f2b(acc[5]) << 16);
    o.w = (uint32_t)f2b(acc[6]) | ((uint32_t)f2b(acc[7]) << 16);
    *(uint4*)&out[((size_t)b * V_ + v) * HID_ + c0] = o;
  }
}

// ---------------- MFMA GEMM ----------------
// PRO: 0=plain bf16 A, 1=GroupNorm(A), 2=FiLM+relu(A)
// EPI: 0=store bf16, 1=bias+relu->bf16, 2=bias + x residual -> f32
template<int PRO, int EPI, int K, int N>
__global__ __launch_bounds__(256) void k_gemm(
    const u16* __restrict__ A, const u16* __restrict__ WT,
    const float* __restrict__ bias, const float* __restrict__ stats,
    const float* __restrict__ gng, const float* __restrict__ gnb,
    const float* __restrict__ gb, const float* __restrict__ xres,
    void* __restrict__ Out)
{
  constexpr int BM = 128, BN = 64, BK = 32;
  __shared__ u16 As[BM][BK + 8];
  __shared__ u16 Bs[BN][BK + 8];
  const int tile_m = blockIdx.x * BM;
  const int n0 = blockIdx.y * BN;
  const int tid = threadIdx.x;
  const int wave = tid >> 6, lane = tid & 63;
  const int wm = (wave >> 1) * 64, wn = (wave & 1) * 32;
  const int lr = lane & 15, lk = (lane >> 4) * 8;

  f32x4 acc[4][2];
#pragma unroll
  for (int i = 0; i < 4; ++i)
#pragma unroll
    for (int j = 0; j < 2; ++j) acc[i][j] = {0.f, 0.f, 0.f, 0.f};

  for (int kb = 0; kb < K; kb += BK) {
    // stage A tile (128x32 bf16)
#pragma unroll
    for (int it = 0; it < 2; ++it) {
      int c = tid + it * 256;
      int r = c >> 2, kq = (c & 3) * 8;
      int row = tile_m + r;
      uint4 val = {0u, 0u, 0u, 0u};
      if (row < M_) {
        val = *(const uint4*)&A[(size_t)row * K + kb + kq];
        if (PRO != 0) {
          int b = (row >= V_) ? 1 : 0;
          u16 us[8]; *(uint4*)us = val;
          float f[8];
#pragma unroll
          for (int j = 0; j < 8; ++j) f[j] = b2f(us[j]);
          if (PRO == 1) {
            float mu = stats[b * 2], rs = stats[b * 2 + 1];
#pragma unroll
            for (int j = 0; j < 8; ++j) {
              int ch = kb + kq + j;
              f[j] = (f[j] - mu) * rs * gng[ch] + gnb[ch];
            }
          } else {
#pragma unroll
            for (int j = 0; j < 8; ++j) {
              int ch = kb + kq + j;
              float y = f[j] * gb[b * 512 + ch] + gb[b * 512 + 256 + ch];
              f[j] = fmaxf(y, 0.f);
            }
          }
#pragma unroll
          for (int j = 0; j < 8; ++j) us[j] = f2b(f[j]);
          val = *(const uint4*)us;
        }
      }
      *(uint4*)&As[r][kq] = val;
    }
    // stage B tile (64x32 bf16) from pre-transposed WT [N][K]
    {
      int r = tid >> 2, kq = (tid & 3) * 8;
      uint4 val = *(const uint4*)&WT[(size_t)(n0 + r) * K + kb + kq];
      *(uint4*)&Bs[r][kq] = val;
    }
    __syncthreads();
    bf16x8 af[4], bfv[2];
#pragma unroll
    for (int fm = 0; fm < 4; ++fm) af[fm] = *(const bf16x8*)&As[wm + fm * 16 + lr][lk];
#pragma unroll
    for (int fn = 0; fn < 2; ++fn) bfv[fn] = *(const bf16x8*)&Bs[wn + fn * 16 + lr][lk];
#pragma unroll
    for (int fm = 0; fm < 4; ++fm)
#pragma unroll
      for (int fn = 0; fn < 2; ++fn)
        acc[fm][fn] = __builtin_amdgcn_mfma_f32_16x16x32_bf16(af[fm], bfv[fn], acc[fm][fn], 0, 0, 0);
    __syncthreads();
  }

#pragma unroll
  for (int fm = 0; fm < 4; ++fm) {
#pragma unroll
    for (int fn = 0; fn < 2; ++fn) {
#pragma unroll
      for (int j = 0; j < 4; ++j) {
        int row = tile_m + wm + fm * 16 + (lane >> 4) * 4 + j;
        int col = n0 + wn + fn * 16 + lr;
        if (row < M_) {
          float v = acc[fm][fn][j];
          if (EPI == 0) {
            ((u16*)Out)[(size_t)row * N + col] = f2b(v);
          } else if (EPI == 1) {
            v += bias[col]; v = fmaxf(v, 0.f);
            ((u16*)Out)[(size_t)row * N + col] = f2b(v);
          } else {
            v += bias[col] + xres[(size_t)row * N + col];
            ((float*)Out)[(size_t)row * N + col] = v;
          }
        }
      }
    }
  }
}

// ---------------- host ----------------
extern "C" void kernel_launch(void* const* d_in, const int* in_sizes, int n_in,
                              void* d_out, int out_size, void* d_ws, size_t ws_size,
                              hipStream_t stream) {
  (void)in_sizes; (void)n_in; (void)out_size; (void)ws_size;
  const float* x      = (const float*)d_in[0];
  const float* cond_x = (const float*)d_in[1];
  const float* t      = (const float*)d_in[3];
  const int*   ei     = (const int*)d_in[4];
  const float* w_c0 = (const float*)d_in[5];  const float* b_c0 = (const float*)d_in[6];
  const float* w_l0 = (const float*)d_in[7];  const float* b_l0 = (const float*)d_in[8];
  const float* w_c1 = (const float*)d_in[9];  const float* b_c1 = (const float*)d_in[10];
  const float* w_l1 = (const float*)d_in[11]; const float* b_l1 = (const float*)d_in[12];
  const float* w_c2 = (const float*)d_in[13]; const float* b_c2 = (const float*)d_in[14];
  const float* w_l2 = (const float*)d_in[15]; const float* b_l2 = (const float*)d_in[16];
  const float* gn_g = (const float*)d_in[17]; const float* gn_b = (const float*)d_in[18];
  const float* film_w = (const float*)d_in[19]; const float* film_b = (const float*)d_in[20];

  char* wsp = (char*)d_ws;
  size_t off = 0;
  auto alloc = [&](size_t bytes) -> char* {
    char* p = wsp + off; off += (bytes + 255) & ~(size_t)255; return p;
  };
  int*   cnt       = (int*)  alloc((size_t)V_ * 4);
  int*   row_ptr   = (int*)  alloc((size_t)(V_ + 1) * 4);
  int*   cursor    = (int*)  alloc((size_t)V_ * 4);
  int*   csr_src   = (int*)  alloc((size_t)E_ * 4);
  float* dinv      = (float*)alloc((size_t)V_ * 4);
  float* stats_raw = (float*)alloc(16);
  float* stats     = (float*)alloc(16);
  float* gb        = (float*)alloc(2 * 512 * 4);
  u16* wc0T = (u16*)alloc((size_t)256 * 160 * 2);
  u16* wl0T = (u16*)alloc((size_t)256 * 256 * 2);
  u16* wc1T = (u16*)alloc((size_t)256 * 256 * 2);
  u16* wl1T = (u16*)alloc((size_t)256 * 256 * 2);
  u16* wc2T = (u16*)alloc((size_t)256 * 256 * 2);
  u16* wl2T = (u16*)alloc((size_t)128 * 256 * 2);
  u16* A0   = (u16*)alloc((size_t)M_ * K0_ * 2);
  u16* HW   = (u16*)alloc((size_t)M_ * HID_ * 2);
  u16* HA   = (u16*)alloc((size_t)M_ * HID_ * 2);
  u16* HB   = (u16*)alloc((size_t)M_ * HID_ * 2);

  const int* srcI = ei;
  const int* dstI = ei + E_;

  hipMemsetAsync(cnt, 0, (size_t)V_ * 4, stream);
  hipMemsetAsync(stats_raw, 0, 16, stream);

  k_count<<<dim3((E_ + 255) / 256), dim3(256), 0, stream>>>(dstI, cnt);
  k_dinv <<<dim3((V_ + 255) / 256), dim3(256), 0, stream>>>(cnt, dinv);
  k_scan <<<dim3(1), dim3(1024), 0, stream>>>(cnt, row_ptr, cursor);
  k_fill <<<dim3((E_ + 255) / 256), dim3(256), 0, stream>>>(srcI, dstI, cursor, csr_src);
  k_film <<<dim3(2), dim3(512), 0, stream>>>(t, film_w, film_b, gb);

  k_wconv<<<dim3((160 * 256 + 255) / 256), dim3(256), 0, stream>>>(w_c0, wc0T, 160, 256);
  k_wconv<<<dim3((256 * 256 + 255) / 256), dim3(256), 0, stream>>>(w_l0, wl0T, 256, 256);
  k_wconv<<<dim3((256 * 256 + 255) / 256), dim3(256), 0, stream>>>(w_c1, wc1T, 256, 256);
  k_wconv<<<dim3((256 * 256 + 255) / 256), dim3(256), 0, stream>>>(w_l1, wl1T, 256, 256);
  k_wconv<<<dim3((256 * 256 + 255) / 256), dim3(256), 0, stream>>>(w_c2, wc2T, 256, 256);
  k_wconv<<<dim3((256 * 128 + 255) / 256), dim3(256), 0, stream>>>(w_l2, wl2T, 256, 128);

  k_prep0<<<dim3(M_ * K0_ / 4 / 256), dim3(256), 0, stream>>>(x, cond_x, A0);

  constexpr int GM = (M_ + 127) / 128;  // 782

  // layer 0: GCN(concat) -> relu ; Lin0 -> relu
  k_gemm<0, 0, 160, 256><<<dim3(GM, 4), 256, 0, stream>>>(A0, wc0T, nullptr, nullptr, nullptr, nullptr, nullptr, nullptr, HW);
  k_gather<<<dim3(V_), 256, 0, stream>>>(HW, dinv, row_ptr, csr_src, b_c0, HA, 1);
  k_gemm<0, 1, 256, 256><<<dim3(GM, 4), 256, 0, stream>>>(HA, wl0T, b_l0, nullptr, nullptr, nullptr, nullptr, nullptr, HB);

  // GroupNorm stats (normalization fused into next GEMM's A-load)
  k_gnstats<<<dim3(1024, 2), 256, 0, stream>>>(HB, stats_raw);
  k_gnfinal<<<dim3(1), dim3(1), 0, stream>>>(stats_raw, stats);

  // layer 1: GCN(gn(h)) -> relu ; Lin1 -> relu
  k_gemm<1, 0, 256, 256><<<dim3(GM, 4), 256, 0, stream>>>(HB, wc1T, nullptr, stats, gn_g, gn_b, nullptr, nullptr, HW);
  k_gather<<<dim3(V_), 256, 0, stream>>>(HW, dinv, row_ptr, csr_src, b_c1, HA, 1);
  k_gemm<0, 1, 256, 256><<<dim3(GM, 4), 256, 0, stream>>>(HA, wl1T, b_l1, nullptr, nullptr, nullptr, nullptr, nullptr, HB);

  // layer 2: GCN (bias, no relu) ; FiLM+relu fused into final GEMM A-load
  k_gemm<0, 0, 256, 256><<<dim3(GM, 4), 256, 0, stream>>>(HB, wc2T, nullptr, nullptr, nullptr, nullptr, nullptr, nullptr, HW);
  k_gather<<<dim3(V_), 256, 0, stream>>>(HW, dinv, row_ptr, csr_src, b_c2, HA, 0);
  k_gemm<2, 2, 256, 128><<<dim3(GM, 2), 256, 0, stream>>>(HA, wl2T, b_l2, nullptr, nullptr, nullptr, gb, x, (void*)d_out);
}

// Round 4
// 671.951 us; speedup vs baseline: 1.3461x; 1.2393x over previous
//
#include <hip/hip_runtime.h>
#include <stdint.h>

typedef unsigned short u16;
typedef short bf16x8 __attribute__((ext_vector_type(8)));
typedef float f32x4 __attribute__((ext_vector_type(4)));

constexpr int B_ = 2, V_ = 50000, E_ = 400000;
constexpr int FIN_ = 128, COND_ = 32, HID_ = 256, OUT_ = 128, ENC_ = 64;
constexpr int M_ = B_ * V_;          // 100000
constexpr int MP_ = M_ + 128;        // padded rows for glds staging overrun
constexpr int K0_ = FIN_ + COND_;    // 160
constexpr float EPS_ = 1e-5f;

#define DEV static __device__ __forceinline__

DEV float b2f(u16 u) { union { float f; uint32_t i; } x; x.i = ((uint32_t)u) << 16; return x.f; }
DEV u16 f2b(float f) {
  union { float f; uint32_t i; } x; x.f = f;
  uint32_t r = x.i + 0x7fffu + ((x.i >> 16) & 1u);
  return (u16)(r >> 16);
}

#define GLDS16(gp, lp) __builtin_amdgcn_global_load_lds( \
    (const __attribute__((address_space(1))) void*)(gp), \
    (__attribute__((address_space(3))) void*)(lp), 16, 0, 0)

// ---------------- graph preprocessing ----------------
__global__ void k_count(const int* __restrict__ dst, int* __restrict__ cnt) {
  int e = blockIdx.x * blockDim.x + threadIdx.x;
  if (e < E_) atomicAdd(&cnt[dst[e]], 1);
}

__global__ void k_dinv(const int* __restrict__ cnt, float* __restrict__ dinv) {
  int v = blockIdx.x * blockDim.x + threadIdx.x;
  if (v < V_) dinv[v] = rsqrtf(1.0f + (float)cnt[v]);
}

// hierarchical scan: 49 blocks of 1024
__global__ __launch_bounds__(1024) void k_scan1(const int* __restrict__ cnt,
                                                int* __restrict__ tmp, int* __restrict__ bsum) {
  __shared__ int s[1024];
  int tid = threadIdx.x;
  int i = blockIdx.x * 1024 + tid;
  int v = (i < V_) ? cnt[i] : 0;
  s[tid] = v;
  __syncthreads();
  for (int off = 1; off < 1024; off <<= 1) {
    int t = (tid >= off) ? s[tid - off] : 0;
    __syncthreads();
    s[tid] += t;
    __syncthreads();
  }
  if (i < V_) tmp[i] = s[tid];
  if (tid == 1023) bsum[blockIdx.x] = s[1023];
}

__global__ void k_scan2(int* __restrict__ bsum, int n) {
  if (threadIdx.x == 0) {
    int a = 0;
    for (int i = 0; i < n; ++i) { a += bsum[i]; bsum[i] = a; }
  }
}

__global__ void k_scan3(const int* __restrict__ cnt, const int* __restrict__ tmp,
                        const int* __restrict__ bsum, int* __restrict__ row_ptr,
                        int* __restrict__ cursor) {
  int i = blockIdx.x * blockDim.x + threadIdx.x;
  if (i >= V_) return;
  int blk = i >> 10;
  int offs = blk ? bsum[blk - 1] : 0;
  int incl = tmp[i] + offs;
  row_ptr[i + 1] = incl;
  cursor[i] = incl - cnt[i];
  if (i == 0) row_ptr[0] = 0;
}

__global__ void k_fill(const int* __restrict__ src, const int* __restrict__ dst,
                       int* __restrict__ cursor, int* __restrict__ csr_src) {
  int e = blockIdx.x * blockDim.x + threadIdx.x;
  if (e < E_) {
    int p = atomicAdd(&cursor[dst[e]], 1);
    csr_src[p] = src[e];
  }
}

// ---------------- small dense helpers ----------------
__global__ void k_film(const float* __restrict__ t, const float* __restrict__ fw,
                       const float* __restrict__ fb, float* __restrict__ gb) {
  int b = blockIdx.x; int j = threadIdx.x;   // blockDim = 512
  float acc = fb[j];
  for (int k = 0; k < ENC_; ++k) acc += t[b * ENC_ + k] * fw[k * 512 + j];
  gb[b * 512 + j] = acc;
}

__global__ void k_wconv(const float* __restrict__ W, u16* __restrict__ WT, int K, int N) {
  int idx = blockIdx.x * blockDim.x + threadIdx.x;
  if (idx < K * N) {
    int k = idx / N, n = idx % N;
    WT[n * K + k] = f2b(W[idx]);
  }
}

// gamma-scaled weight transpose (GroupNorm fold)
__global__ void k_wconv_g(const float* __restrict__ W, const float* __restrict__ gng,
                          u16* __restrict__ WT, int K, int N) {
  int idx = blockIdx.x * blockDim.x + threadIdx.x;
  if (idx < K * N) {
    int k = idx / N, n = idx % N;
    WT[n * K + k] = f2b(W[idx] * gng[k]);
  }
}

// kc[b][n] = (gnb @ W)[n] - mu_b*rs_b*(gng @ W)[n]   (after stats known)
__global__ void k_gnfold(const float* __restrict__ gng, const float* __restrict__ gnb,
                         const float* __restrict__ W, const float* __restrict__ stats,
                         float* __restrict__ kc) {
  int n = threadIdx.x;  // 256 threads, 1 block
  float gw = 0.f, bw = 0.f;
  for (int c = 0; c < HID_; ++c) {
    float wv = W[c * HID_ + n];
    gw += gng[c] * wv;
    bw += gnb[c] * wv;
  }
  for (int b = 0; b < B_; ++b)
    kc[b * HID_ + n] = bw - stats[b * 2] * stats[b * 2 + 1] * gw;
}

__global__ void k_prep0(const float* __restrict__ x, const float* __restrict__ cond,
                        u16* __restrict__ A0) {
  int idx = blockIdx.x * blockDim.x + threadIdx.x; // chunk of 4 elements
  if (idx >= M_ * K0_ / 4) return;
  int e = idx * 4;
  int r = e / K0_, c = e % K0_;
  float4 v;
  if (c < FIN_) v = *(const float4*)&x[(size_t)r * FIN_ + c];
  else { int vv = r % V_; v = *(const float4*)&cond[(size_t)vv * COND_ + (c - FIN_)]; }
  uint2 o;
  o.x = (uint32_t)f2b(v.x) | ((uint32_t)f2b(v.y) << 16);
  o.y = (uint32_t)f2b(v.z) | ((uint32_t)f2b(v.w) << 16);
  *(uint2*)&A0[e] = o;
}

// ---------------- GroupNorm stats ----------------
__global__ void k_gnstats(const u16* __restrict__ h, float* __restrict__ raw) {
  int b = blockIdx.y;
  const u16* p = h + (size_t)b * V_ * HID_;
  const int nvec = V_ * HID_ / 8;
  float s = 0.f, ss = 0.f;
  for (int i = blockIdx.x * blockDim.x + threadIdx.x; i < nvec; i += gridDim.x * blockDim.x) {
    uint4 u = *(const uint4*)&p[(size_t)i * 8];
    u16 us[8]; *(uint4*)us = u;
#pragma unroll
    for (int j = 0; j < 8; ++j) { float f = b2f(us[j]); s += f; ss += f * f; }
  }
  __shared__ float ls[256], lss[256];
  ls[threadIdx.x] = s; lss[threadIdx.x] = ss;
  __syncthreads();
  for (int off = 128; off > 0; off >>= 1) {
    if (threadIdx.x < off) { ls[threadIdx.x] += ls[threadIdx.x + off]; lss[threadIdx.x] += lss[threadIdx.x + off]; }
    __syncthreads();
  }
  if (threadIdx.x == 0) {
    atomicAdd(&raw[b * 2 + 0], ls[0]);
    atomicAdd(&raw[b * 2 + 1], lss[0]);
  }
}

__global__ void k_gnfinal(const float* __restrict__ raw, float* __restrict__ stats) {
  for (int b = 0; b < B_; ++b) {
    float n = (float)V_ * (float)HID_;
    float mu = raw[b * 2] / n;
    float var = raw[b * 2 + 1] / n - mu * mu;
    stats[b * 2 + 0] = mu;
    stats[b * 2 + 1] = rsqrtf(var + EPS_);
  }
}

// ---------------- GCN gather (CSR, neighbor-parallel, 2-deep MLP) ----------------
// 256 threads = [nb=4 groups (waves)] x [b=2 batches] x [32 ch threads x 8ch]
__global__ __launch_bounds__(256) void k_gather(
    const u16* __restrict__ hw, const float* __restrict__ dinv,
    const int* __restrict__ row_ptr, const int* __restrict__ csr_src,
    const float* __restrict__ bias, u16* __restrict__ out, int do_relu)
{
  __shared__ f32x4 redA[3][2][32];   // contiguous 16B/lane writes: conflict-free
  __shared__ f32x4 redB[3][2][32];
  const int v   = blockIdx.x;
  const int tid = threadIdx.x;
  const int nb  = tid >> 6;          // wave id: neighbor group 0..3
  const int b   = (tid >> 5) & 1;    // batch
  const int l   = tid & 31;
  const int c0  = l * 8;             // channel base (8 per thread)

  const float dv = dinv[v];
  const int beg = row_ptr[v], end = row_ptr[v + 1];

  float acc[8];
#pragma unroll
  for (int k = 0; k < 8; ++k) acc[k] = 0.f;

  int j = beg + nb;
  for (; j + 4 < end; j += 8) {
    int s0 = csr_src[j];
    int s1 = csr_src[j + 4];
    float cf0 = dinv[s0] * dv;
    float cf1 = dinv[s1] * dv;
    uint4 u0 = *(const uint4*)&hw[((size_t)b * V_ + s0) * HID_ + c0];
    uint4 u1 = *(const uint4*)&hw[((size_t)b * V_ + s1) * HID_ + c0];
    u16 a0[8]; *(uint4*)a0 = u0;
    u16 a1[8]; *(uint4*)a1 = u1;
#pragma unroll
    for (int k = 0; k < 8; ++k) acc[k] += b2f(a0[k]) * cf0;
#pragma unroll
    for (int k = 0; k < 8; ++k) acc[k] += b2f(a1[k]) * cf1;
  }
  if (j < end) {
    int s0 = csr_src[j];
    float cf0 = dinv[s0] * dv;
    uint4 u0 = *(const uint4*)&hw[((size_t)b * V_ + s0) * HID_ + c0];
    u16 a0[8]; *(uint4*)a0 = u0;
#pragma unroll
    for (int k = 0; k < 8; ++k) acc[k] += b2f(a0[k]) * cf0;
  }

  if (nb > 0) {
    redA[nb - 1][b][l] = f32x4{acc[0], acc[1], acc[2], acc[3]};
    redB[nb - 1][b][l] = f32x4{acc[4], acc[5], acc[6], acc[7]};
  }
  __syncthreads();
  if (nb == 0) {
#pragma unroll
    for (int g = 0; g < 3; ++g) {
      f32x4 ra = redA[g][b][l], rb = redB[g][b][l];
      acc[0] += ra[0]; acc[1] += ra[1]; acc[2] += ra[2]; acc[3] += ra[3];
      acc[4] += rb[0]; acc[5] += rb[1]; acc[6] += rb[2]; acc[7] += rb[3];
    }
    // self-loop + bias (+ relu)
    float sl = dv * dv;
    uint4 u = *(const uint4*)&hw[((size_t)b * V_ + v) * HID_ + c0];
    u16 us[8]; *(uint4*)us = u;
#pragma unroll
    for (int k = 0; k < 8; ++k) {
      float a = acc[k] + b2f(us[k]) * sl + bias[c0 + k];
      if (do_relu) a = fmaxf(a, 0.f);
      acc[k] = a;
    }
    uint4 o;
    o.x = (uint32_t)f2b(acc[0]) | ((uint32_t)f2b(acc[1]) << 16);
    o.y = (uint32_t)f2b(acc[2]) | ((uint32_t)f2b(acc[3]) << 16);
    o.z = (uint32_t)f2b(acc[4]) | ((uint32_t)f2b(acc[5]) << 16);
    o.w = (uint32_t)f2b(acc[6]) | ((uint32_t)f2b(acc[7]) << 16);
    *(uint4*)&out[((size_t)b * V_ + v) * HID_ + c0] = o;
  }
}

// ---------------- glds MFMA GEMM: 128x128 tile, BK=32 ----------------
// EPI: 0=store bf16, 1=bias+relu->bf16, 3=rs_b*v + kc[b][n] -> bf16 (GN fold)
// LDS layout: linear 64B rows, 16B slot s stored at s ^ ((row>>1)&3) via
// pre-swizzled global source (both-sides involution; rule 21).
template<int EPI, int K, int N>
__global__ __launch_bounds__(256) void k_gemm_g(
    const u16* __restrict__ A, const u16* __restrict__ WT,
    const float* __restrict__ bias,     // EPI1: bias[N]; EPI3: kc[2][N]
    const float* __restrict__ stats,    // EPI3: {mu,rs}x2
    u16* __restrict__ Out)
{
  constexpr int BM = 128, BN = 128, BK = 32;
  __shared__ alignas(16) u16 As[BM * BK];
  __shared__ alignas(16) u16 Bs[BN * BK];
  const int tile_m = blockIdx.x * BM;
  const int n0 = blockIdx.y * BN;
  const int tid = threadIdx.x;
  const int wave = tid >> 6, lane = tid & 63;
  const int wm = (wave >> 1) * 64, wn = (wave & 1) * 64;
  const int lr = lane & 15, lkg = lane >> 4;
  const int phys = lkg ^ ((lr >> 1) & 3);   // swizzled 16B slot for frag reads

  f32x4 acc[4][4];
#pragma unroll
  for (int i = 0; i < 4; ++i)
#pragma unroll
    for (int jj = 0; jj < 4; ++jj) acc[i][jj] = {0.f, 0.f, 0.f, 0.f};

  for (int kb = 0; kb < K; kb += BK) {
    // stage A: 128 rows x 64B, 2 rounds of 256 lanes x 16B
#pragma unroll
    for (int it = 0; it < 2; ++it) {
      int c = tid + it * 256;
      int row = c >> 2;
      int sslot = (c & 3) ^ ((row >> 1) & 3);
      const u16* gA = A + (size_t)(tile_m + row) * K + kb + sslot * 8;
      GLDS16(gA, &As[(it * 256 + wave * 64) * 8]);
    }
    // stage B: 128 rows x 64B
#pragma unroll
    for (int it = 0; it < 2; ++it) {
      int c = tid + it * 256;
      int row = c >> 2;
      int sslot = (c & 3) ^ ((row >> 1) & 3);
      const u16* gB = WT + (size_t)(n0 + row) * K + kb + sslot * 8;
      GLDS16(gB, &Bs[(it * 256 + wave * 64) * 8]);
    }
    __syncthreads();
    bf16x8 af[4], bf[4];
#pragma unroll
    for (int fm = 0; fm < 4; ++fm) af[fm] = *(const bf16x8*)&As[(wm + fm * 16 + lr) * BK + phys * 8];
#pragma unroll
    for (int fn = 0; fn < 4; ++fn) bf[fn] = *(const bf16x8*)&Bs[(wn + fn * 16 + lr) * BK + phys * 8];
#pragma unroll
    for (int fm = 0; fm < 4; ++fm)
#pragma unroll
      for (int fn = 0; fn < 4; ++fn)
        acc[fm][fn] = __builtin_amdgcn_mfma_f32_16x16x32_bf16(af[fm], bf[fn], acc[fm][fn], 0, 0, 0);
    __syncthreads();
  }

#pragma unroll
  for (int fm = 0; fm < 4; ++fm) {
#pragma unroll
    for (int fn = 0; fn < 4; ++fn) {
#pragma unroll
      for (int j = 0; j < 4; ++j) {
        int row = tile_m + wm + fm * 16 + lkg * 4 + j;
        int col = n0 + wn + fn * 16 + lr;
        if (row < M_) {
          float v = acc[fm][fn][j];
          if (EPI == 1) { v += bias[col]; v = fmaxf(v, 0.f); }
          else if (EPI == 3) {
            int bb = (row >= V_) ? 1 : 0;
            v = v * stats[bb * 2 + 1] + bias[bb * N + col];
          }
          Out[(size_t)row * N + col] = f2b(v);
        }
      }
    }
  }
}

// ---------------- old-path MFMA GEMM (final FiLM GEMM only) ----------------
template<int K, int N>
__global__ __launch_bounds__(256) void k_gemm_film(
    const u16* __restrict__ A, const u16* __restrict__ WT,
    const float* __restrict__ bias, const float* __restrict__ gb,
    const float* __restrict__ xres, float* __restrict__ Out)
{
  constexpr int BM = 128, BN = 64, BK = 32;
  __shared__ u16 As[BM][BK + 8];
  __shared__ u16 Bs[BN][BK + 8];
  const int tile_m = blockIdx.x * BM;
  const int n0 = blockIdx.y * BN;
  const int tid = threadIdx.x;
  const int wave = tid >> 6, lane = tid & 63;
  const int wm = (wave >> 1) * 64, wn = (wave & 1) * 32;
  const int lr = lane & 15, lk = (lane >> 4) * 8;

  f32x4 acc[4][2];
#pragma unroll
  for (int i = 0; i < 4; ++i)
#pragma unroll
    for (int j = 0; j < 2; ++j) acc[i][j] = {0.f, 0.f, 0.f, 0.f};

  for (int kb = 0; kb < K; kb += BK) {
#pragma unroll
    for (int it = 0; it < 2; ++it) {
      int c = tid + it * 256;
      int r = c >> 2, kq = (c & 3) * 8;
      int row = tile_m + r;
      uint4 val = {0u, 0u, 0u, 0u};
      if (row < M_) {
        val = *(const uint4*)&A[(size_t)row * K + kb + kq];
        int b = (row >= V_) ? 1 : 0;
        u16 us[8]; *(uint4*)us = val;
        float f[8];
#pragma unroll
        for (int j = 0; j < 8; ++j) f[j] = b2f(us[j]);
#pragma unroll
        for (int j = 0; j < 8; ++j) {
          int ch = kb + kq + j;
          float y = f[j] * gb[b * 512 + ch] + gb[b * 512 + 256 + ch];
          f[j] = fmaxf(y, 0.f);
        }
#pragma unroll
        for (int j = 0; j < 8; ++j) us[j] = f2b(f[j]);
        val = *(const uint4*)us;
      }
      *(uint4*)&As[r][kq] = val;
    }
    {
      int r = tid >> 2, kq = (tid & 3) * 8;
      uint4 val = *(const uint4*)&WT[(size_t)(n0 + r) * K + kb + kq];
      *(uint4*)&Bs[r][kq] = val;
    }
    __syncthreads();
    bf16x8 af[4], bfv[2];
#pragma unroll
    for (int fm = 0; fm < 4; ++fm) af[fm] = *(const bf16x8*)&As[wm + fm * 16 + lr][lk];
#pragma unroll
    for (int fn = 0; fn < 2; ++fn) bfv[fn] = *(const bf16x8*)&Bs[wn + fn * 16 + lr][lk];
#pragma unroll
    for (int fm = 0; fm < 4; ++fm)
#pragma unroll
      for (int fn = 0; fn < 2; ++fn)
        acc[fm][fn] = __builtin_amdgcn_mfma_f32_16x16x32_bf16(af[fm], bfv[fn], acc[fm][fn], 0, 0, 0);
    __syncthreads();
  }

#pragma unroll
  for (int fm = 0; fm < 4; ++fm) {
#pragma unroll
    for (int fn = 0; fn < 2; ++fn) {
#pragma unroll
      for (int j = 0; j < 4; ++j) {
        int row = tile_m + wm + fm * 16 + (lane >> 4) * 4 + j;
        int col = n0 + wn + fn * 16 + lr;
        if (row < M_) {
          float v = acc[fm][fn][j] + bias[col] + xres[(size_t)row * N + col];
          Out[(size_t)row * N + col] = v;
        }
      }
    }
  }
}

// ---------------- host ----------------
extern "C" void kernel_launch(void* const* d_in, const int* in_sizes, int n_in,
                              void* d_out, int out_size, void* d_ws, size_t ws_size,
                              hipStream_t stream) {
  (void)in_sizes; (void)n_in; (void)out_size; (void)ws_size;
  const float* x      = (const float*)d_in[0];
  const float* cond_x = (const float*)d_in[1];
  const float* t      = (const float*)d_in[3];
  const int*   ei     = (const int*)d_in[4];
  const float* w_c0 = (const float*)d_in[5];  const float* b_c0 = (const float*)d_in[6];
  const float* w_l0 = (const float*)d_in[7];  const float* b_l0 = (const float*)d_in[8];
  const float* w_c1 = (const float*)d_in[9];  const float* b_c1 = (const float*)d_in[10];
  const float* w_l1 = (const float*)d_in[11]; const float* b_l1 = (const float*)d_in[12];
  const float* w_c2 = (const float*)d_in[13]; const float* b_c2 = (const float*)d_in[14];
  const float* w_l2 = (const float*)d_in[15]; const float* b_l2 = (const float*)d_in[16];
  const float* gn_g = (const float*)d_in[17]; const float* gn_b = (const float*)d_in[18];
  const float* film_w = (const float*)d_in[19]; const float* film_b = (const float*)d_in[20];

  char* wsp = (char*)d_ws;
  size_t off = 0;
  auto alloc = [&](size_t bytes) -> char* {
    char* p = wsp + off; off += (bytes + 255) & ~(size_t)255; return p;
  };
  int*   cnt       = (int*)  alloc((size_t)V_ * 4);
  int*   row_ptr   = (int*)  alloc((size_t)(V_ + 1) * 4);
  int*   cursor    = (int*)  alloc((size_t)V_ * 4);
  int*   csr_src   = (int*)  alloc((size_t)E_ * 4);
  int*   scan_tmp  = (int*)  alloc((size_t)V_ * 4);
  int*   scan_bsum = (int*)  alloc(64 * 4);
  float* dinv      = (float*)alloc((size_t)V_ * 4);
  float* stats_raw = (float*)alloc(16);
  float* stats     = (float*)alloc(16);
  float* gb        = (float*)alloc(2 * 512 * 4);
  float* kc        = (float*)alloc(2 * HID_ * 4);
  u16* wc0T  = (u16*)alloc((size_t)256 * 160 * 2);
  u16* wl0T  = (u16*)alloc((size_t)256 * 256 * 2);
  u16* wc1Tg = (u16*)alloc((size_t)256 * 256 * 2);
  u16* wl1T  = (u16*)alloc((size_t)256 * 256 * 2);
  u16* wc2T  = (u16*)alloc((size_t)256 * 256 * 2);
  u16* wl2T  = (u16*)alloc((size_t)128 * 256 * 2);
  u16* A0    = (u16*)alloc((size_t)MP_ * K0_ * 2);
  u16* HW    = (u16*)alloc((size_t)MP_ * HID_ * 2);
  u16* HA    = (u16*)alloc((size_t)MP_ * HID_ * 2);
  u16* HB    = (u16*)alloc((size_t)MP_ * HID_ * 2);

  const int* srcI = ei;
  const int* dstI = ei + E_;

  hipMemsetAsync(cnt, 0, (size_t)V_ * 4, stream);
  hipMemsetAsync(stats_raw, 0, 16, stream);

  constexpr int NBLK = (V_ + 1023) / 1024;  // 49
  k_count<<<dim3((E_ + 255) / 256), dim3(256), 0, stream>>>(dstI, cnt);
  k_dinv <<<dim3((V_ + 255) / 256), dim3(256), 0, stream>>>(cnt, dinv);
  k_scan1<<<dim3(NBLK), dim3(1024), 0, stream>>>(cnt, scan_tmp, scan_bsum);
  k_scan2<<<dim3(1), dim3(64), 0, stream>>>(scan_bsum, NBLK);
  k_scan3<<<dim3((V_ + 255) / 256), dim3(256), 0, stream>>>(cnt, scan_tmp, scan_bsum, row_ptr, cursor);
  k_fill <<<dim3((E_ + 255) / 256), dim3(256), 0, stream>>>(srcI, dstI, cursor, csr_src);
  k_film <<<dim3(2), dim3(512), 0, stream>>>(t, film_w, film_b, gb);

  k_wconv  <<<dim3((160 * 256 + 255) / 256), dim3(256), 0, stream>>>(w_c0, wc0T, 160, 256);
  k_wconv  <<<dim3((256 * 256 + 255) / 256), dim3(256), 0, stream>>>(w_l0, wl0T, 256, 256);
  k_wconv_g<<<dim3((256 * 256 + 255) / 256), dim3(256), 0, stream>>>(w_c1, gn_g, wc1Tg, 256, 256);
  k_wconv  <<<dim3((256 * 256 + 255) / 256), dim3(256), 0, stream>>>(w_l1, wl1T, 256, 256);
  k_wconv  <<<dim3((256 * 256 + 255) / 256), dim3(256), 0, stream>>>(w_c2, wc2T, 256, 256);
  k_wconv  <<<dim3((256 * 128 + 255) / 256), dim3(256), 0, stream>>>(w_l2, wl2T, 256, 128);

  k_prep0<<<dim3(M_ * K0_ / 4 / 256), dim3(256), 0, stream>>>(x, cond_x, A0);

  constexpr int GM = (M_ + 127) / 128;  // 782

  // layer 0: GCN(concat) -> relu ; Lin0 -> relu
  k_gemm_g<0, 160, 256><<<dim3(GM, 2), 256, 0, stream>>>(A0, wc0T, nullptr, nullptr, HW);
  k_gather<<<dim3(V_), 256, 0, stream>>>(HW, dinv, row_ptr, csr_src, b_c0, HA, 1);
  k_gemm_g<1, 256, 256><<<dim3(GM, 2), 256, 0, stream>>>(HA, wl0T, b_l0, nullptr, HB);

  // GroupNorm stats + weight-fold constants
  k_gnstats<<<dim3(1024, 2), 256, 0, stream>>>(HB, stats_raw);
  k_gnfinal<<<dim3(1), dim3(1), 0, stream>>>(stats_raw, stats);
  k_gnfold <<<dim3(1), dim3(256), 0, stream>>>(gn_g, gn_b, w_c1, stats, kc);

  // layer 1: GCN(gn(h)) folded: rs_b*(HB@Wg) + kc ; gather ; Lin1 -> relu
  k_gemm_g<3, 256, 256><<<dim3(GM, 2), 256, 0, stream>>>(HB, wc1Tg, kc, stats, HW);
  k_gather<<<dim3(V_), 256, 0, stream>>>(HW, dinv, row_ptr, csr_src, b_c1, HA, 1);
  k_gemm_g<1, 256, 256><<<dim3(GM, 2), 256, 0, stream>>>(HA, wl1T, b_l1, nullptr, HB);

  // layer 2: GCN (bias, no relu) ; FiLM+relu fused into final GEMM A-load
  k_gemm_g<0, 256, 256><<<dim3(GM, 2), 256, 0, stream>>>(HB, wc2T, nullptr, nullptr, HW);
  k_gather<<<dim3(V_), 256, 0, stream>>>(HW, dinv, row_ptr, csr_src, b_c2, HA, 0);
  k_gemm_film<256, 128><<<dim3(GM, 2), 256, 0, stream>>>(HA, wl2T, b_l2, gb, x, (float*)d_out);
}